// Round 1
// baseline (313.649 us; speedup 1.0000x reference)
//
#include <hip/hip_runtime.h>

// DBASolver: B=16, N=196608, C=2.
// Pass 1: per-batch reduction of H_eff (21 sym entries) + g_eff (6) -- the
//         Schur term (H_pd * invHdd * H_pd^T) is linear in n, fused in.
// Pass 2: 16x tiny 6x6 Gauss-Jordan solves (diag-dominant SPD, no pivoting).
// Pass 3: per-point delta_depth = invHdd * (g_d - H_pd . dp_unclipped).

constexpr int NACC = 27;  // 21 upper-triangular H entries + 6 g entries

__global__ __launch_bounds__(256) void dba_reduce(
    const float* __restrict__ r, const float* __restrict__ w,
    const float* __restrict__ J_p, const float* __restrict__ J_d,
    const float* __restrict__ lmbda, float* __restrict__ acc, int N)
{
    const int b = blockIdx.y;
    const float lam = lmbda[b];
    float A[21];
    float g[6];
#pragma unroll
    for (int i = 0; i < 21; ++i) A[i] = 0.f;
#pragma unroll
    for (int i = 0; i < 6; ++i) g[i] = 0.f;

    const size_t base = (size_t)b * (size_t)N;
    const int stride = gridDim.x * blockDim.x;
    for (int n = blockIdx.x * blockDim.x + threadIdx.x; n < N; n += stride) {
        const size_t p = base + n;
        const float2 rv = *(const float2*)(r + p * 2);
        const float2 wv = *(const float2*)(w + p * 2);
        const float2 jd = *(const float2*)(J_d + p * 2);
        const float4* jp = (const float4*)(J_p + p * 12);
        const float4 j0 = jp[0];
        const float4 j1 = jp[1];
        const float4 j2 = jp[2];
        const float ja[6] = {j0.x, j0.y, j0.z, j0.w, j1.x, j1.y};  // J_p[k=0][i]
        const float jb[6] = {j1.z, j1.w, j2.x, j2.y, j2.z, j2.w};  // J_p[k=1][i]
        const float conf = wv.x, nlam = wv.y;
        const float jd0 = jd.x, jd1 = jd.y;

        float h[6], gp[6];
#pragma unroll
        for (int i = 0; i < 6; ++i) {
            h[i]  = conf * (ja[i] * jd0 + jb[i] * jd1);   // H_pd[b,n,i]
            gp[i] = conf * (ja[i] * rv.x + jb[i] * rv.y); // g_p contribution
        }
        const float hdd = conf * (jd0 * jd0 + jd1 * jd1);
        const float inv = 1.0f / fmaxf(hdd + lam + nlam, 1e-4f);
        const float gd  = conf * (jd0 * rv.x + jd1 * rv.y);
        const float gdinv = gd * inv;

        int idx = 0;
#pragma unroll
        for (int i = 0; i < 6; ++i) {
            const float hii = h[i] * inv;
#pragma unroll
            for (int j = i; j < 6; ++j) {
                // H_pp contribution minus Schur term contribution
                A[idx] += conf * (ja[i] * ja[j] + jb[i] * jb[j]) - hii * h[j];
                ++idx;
            }
            g[i] += gp[i] - h[i] * gdinv;
        }
    }

    float v[NACC];
#pragma unroll
    for (int i = 0; i < 21; ++i) v[i] = A[i];
#pragma unroll
    for (int i = 0; i < 6; ++i) v[21 + i] = g[i];

    // wave-64 shuffle reduction
#pragma unroll
    for (int off = 32; off > 0; off >>= 1) {
#pragma unroll
        for (int i = 0; i < NACC; ++i) v[i] += __shfl_down(v[i], off, 64);
    }

    __shared__ float sred[4][NACC];
    const int wave = threadIdx.x >> 6;
    const int lane = threadIdx.x & 63;
    if (lane == 0) {
#pragma unroll
        for (int i = 0; i < NACC; ++i) sred[wave][i] = v[i];
    }
    __syncthreads();
    if (threadIdx.x < NACC) {
        const float s = sred[0][threadIdx.x] + sred[1][threadIdx.x] +
                        sred[2][threadIdx.x] + sred[3][threadIdx.x];
        atomicAdd(&acc[b * 32 + threadIdx.x], s);
    }
}

__global__ void dba_solve(const float* __restrict__ acc,
                          const float* __restrict__ lmbda,
                          float* __restrict__ pose_out,
                          float* __restrict__ dp_ws, int B)
{
    const int b = blockIdx.x * blockDim.x + threadIdx.x;
    if (b >= B) return;
    float M[6][7];
    const float* a = acc + b * 32;
    int idx = 0;
#pragma unroll
    for (int i = 0; i < 6; ++i) {
#pragma unroll
        for (int j = i; j < 6; ++j) {
            const float t = a[idx++];
            M[i][j] = t;
            M[j][i] = t;
        }
    }
#pragma unroll
    for (int i = 0; i < 6; ++i) M[i][6] = a[21 + i];
    const float lam = lmbda[b];
#pragma unroll
    for (int i = 0; i < 6; ++i) M[i][i] += lam + 0.011f;  // lmbda*I + (0.01+0.001)*I

    // Gauss-Jordan, no pivoting (matrix strongly diagonally dominant SPD)
#pragma unroll
    for (int k = 0; k < 6; ++k) {
        const float piv = 1.0f / M[k][k];
#pragma unroll
        for (int j = 0; j < 7; ++j) M[k][j] *= piv;
#pragma unroll
        for (int i = 0; i < 6; ++i) {
            if (i == k) continue;
            const float f = M[i][k];
#pragma unroll
            for (int j = 0; j < 7; ++j) M[i][j] -= f * M[k][j];
        }
    }
#pragma unroll
    for (int i = 0; i < 6; ++i) {
        const float x = M[i][6];              // solution
        dp_ws[b * 6 + i] = x;                 // UNCLIPPED dp feeds pass 3
        pose_out[b * 6 + i] = fminf(fmaxf(x, -2.0f), 2.0f);
    }
}

__global__ __launch_bounds__(256) void dba_depth(
    const float* __restrict__ r, const float* __restrict__ w,
    const float* __restrict__ J_p, const float* __restrict__ J_d,
    const float* __restrict__ lmbda, const float* __restrict__ dp_ws,
    float* __restrict__ depth_out, int N)
{
    const int b = blockIdx.y;
    const float lam = lmbda[b];
    float dp[6];
#pragma unroll
    for (int i = 0; i < 6; ++i) dp[i] = dp_ws[b * 6 + i];

    const size_t base = (size_t)b * (size_t)N;
    const int stride = gridDim.x * blockDim.x;
    for (int n = blockIdx.x * blockDim.x + threadIdx.x; n < N; n += stride) {
        const size_t p = base + n;
        const float2 rv = *(const float2*)(r + p * 2);
        const float2 wv = *(const float2*)(w + p * 2);
        const float2 jd = *(const float2*)(J_d + p * 2);
        const float4* jp = (const float4*)(J_p + p * 12);
        const float4 j0 = jp[0];
        const float4 j1 = jp[1];
        const float4 j2 = jp[2];
        const float ja[6] = {j0.x, j0.y, j0.z, j0.w, j1.x, j1.y};
        const float jb[6] = {j1.z, j1.w, j2.x, j2.y, j2.z, j2.w};
        const float conf = wv.x, nlam = wv.y;
        const float jd0 = jd.x, jd1 = jd.y;

        float v = 0.f;
#pragma unroll
        for (int i = 0; i < 6; ++i) {
            const float h = conf * (ja[i] * jd0 + jb[i] * jd1);
            v += h * dp[i];
        }
        const float hdd = conf * (jd0 * jd0 + jd1 * jd1);
        const float inv = 1.0f / fmaxf(hdd + lam + nlam, 1e-4f);
        const float gd  = conf * (jd0 * rv.x + jd1 * rv.y);
        depth_out[p] = inv * (gd - v);
    }
}

extern "C" void kernel_launch(void* const* d_in, const int* in_sizes, int n_in,
                              void* d_out, int out_size, void* d_ws, size_t ws_size,
                              hipStream_t stream)
{
    const float* r   = (const float*)d_in[0];
    const float* w   = (const float*)d_in[1];
    const float* J_p = (const float*)d_in[2];
    const float* J_d = (const float*)d_in[3];
    const float* lmb = (const float*)d_in[4];
    const int B = in_sizes[4];            // 16
    const int N = in_sizes[0] / (B * 2);  // 196608

    float* acc   = (float*)d_ws;           // B*32 floats of accumulators
    float* dp_ws = (float*)d_ws + B * 32;  // B*6 floats of unclipped dp
    float* out   = (float*)d_out;

    hipMemsetAsync(acc, 0, B * 32 * sizeof(float), stream);

    dim3 grid(64, B);  // 64*256 threads per batch -> exactly 12 points/thread
    dba_reduce<<<grid, 256, 0, stream>>>(r, w, J_p, J_d, lmb, acc, N);
    dba_solve<<<1, 64, 0, stream>>>(acc, lmb, out, dp_ws, B);
    dba_depth<<<grid, 256, 0, stream>>>(r, w, J_p, J_d, lmb, dp_ws, out + B * 6, N);
}

// Round 2
// 306.438 us; speedup vs baseline: 1.0235x; 1.0235x over previous
//
#include <hip/hip_runtime.h>

// DBASolver: B=16, N=196608, C=2.
// Pass 1: per-batch reduction of H_eff (21 sym entries) + g_eff (6) -- the
//         Schur term (H_pd * invHdd * H_pd^T) is linear in n, fused in.
// Pass 2: 16x tiny 6x6 Gauss-Jordan solves (diag-dominant SPD, no pivoting).
// Pass 3: per-point delta_depth = invHdd * (g_d - H_pd . dp_unclipped).
//
// R1: pair-processing (2 points/thread/iter) so r/w/J_d become float4 loads;
//     grid.x 64->192 (3072 blocks, ~24 waves/CU resident) to fix the
//     occupancy-bound latency stall seen in R0 (37% occ, 1.2 TB/s).

constexpr int NACC = 27;  // 21 upper-triangular H entries + 6 g entries

__device__ __forceinline__ void accum_point(
    float ja0, float ja1, float ja2, float ja3, float ja4, float ja5,
    float jb0, float jb1, float jb2, float jb3, float jb4, float jb5,
    float r0, float r1, float conf, float nlam, float jd0, float jd1,
    float lam, float* __restrict__ A, float* __restrict__ g)
{
    const float ja[6] = {ja0, ja1, ja2, ja3, ja4, ja5};
    const float jb[6] = {jb0, jb1, jb2, jb3, jb4, jb5};
    float h[6], gp[6];
#pragma unroll
    for (int i = 0; i < 6; ++i) {
        h[i]  = conf * (ja[i] * jd0 + jb[i] * jd1);   // H_pd[b,n,i]
        gp[i] = conf * (ja[i] * r0 + jb[i] * r1);     // g_p contribution
    }
    const float hdd = conf * (jd0 * jd0 + jd1 * jd1);
    const float inv = 1.0f / fmaxf(hdd + lam + nlam, 1e-4f);
    const float gd  = conf * (jd0 * r0 + jd1 * r1);
    const float gdinv = gd * inv;
    int idx = 0;
#pragma unroll
    for (int i = 0; i < 6; ++i) {
        const float hii = h[i] * inv;
#pragma unroll
        for (int j = i; j < 6; ++j) {
            A[idx] += conf * (ja[i] * ja[j] + jb[i] * jb[j]) - hii * h[j];
            ++idx;
        }
        g[i] += gp[i] - h[i] * gdinv;
    }
}

__global__ __launch_bounds__(256) void dba_reduce(
    const float* __restrict__ r, const float* __restrict__ w,
    const float* __restrict__ J_p, const float* __restrict__ J_d,
    const float* __restrict__ lmbda, float* __restrict__ acc, int N)
{
    const int b = blockIdx.y;
    const float lam = lmbda[b];
    float A[21];
    float g[6];
#pragma unroll
    for (int i = 0; i < 21; ++i) A[i] = 0.f;
#pragma unroll
    for (int i = 0; i < 6; ++i) g[i] = 0.f;

    const size_t base = (size_t)b * (size_t)N;
    const int P = N >> 1;  // point pairs
    const int stride = gridDim.x * blockDim.x;
    for (int pr = blockIdx.x * blockDim.x + threadIdx.x; pr < P; pr += stride) {
        const size_t p = base + (size_t)(pr << 1);   // first point of pair
        const float4 rv = *(const float4*)(r + p * 2);    // r[p], r[p+1]
        const float4 wv = *(const float4*)(w + p * 2);    // w[p], w[p+1]
        const float4 jd = *(const float4*)(J_d + p * 2);  // J_d[p], J_d[p+1]
        const float4* jp = (const float4*)(J_p + p * 12); // 6 x float4
        const float4 q0 = jp[0];
        const float4 q1 = jp[1];
        const float4 q2 = jp[2];
        const float4 q3 = jp[3];
        const float4 q4 = jp[4];
        const float4 q5 = jp[5];

        accum_point(q0.x, q0.y, q0.z, q0.w, q1.x, q1.y,
                    q1.z, q1.w, q2.x, q2.y, q2.z, q2.w,
                    rv.x, rv.y, wv.x, wv.y, jd.x, jd.y, lam, A, g);
        accum_point(q3.x, q3.y, q3.z, q3.w, q4.x, q4.y,
                    q4.z, q4.w, q5.x, q5.y, q5.z, q5.w,
                    rv.z, rv.w, wv.z, wv.w, jd.z, jd.w, lam, A, g);
    }

    float v[NACC];
#pragma unroll
    for (int i = 0; i < 21; ++i) v[i] = A[i];
#pragma unroll
    for (int i = 0; i < 6; ++i) v[21 + i] = g[i];

    // wave-64 shuffle reduction
#pragma unroll
    for (int off = 32; off > 0; off >>= 1) {
#pragma unroll
        for (int i = 0; i < NACC; ++i) v[i] += __shfl_down(v[i], off, 64);
    }

    __shared__ float sred[4][NACC];
    const int wave = threadIdx.x >> 6;
    const int lane = threadIdx.x & 63;
    if (lane == 0) {
#pragma unroll
        for (int i = 0; i < NACC; ++i) sred[wave][i] = v[i];
    }
    __syncthreads();
    if (threadIdx.x < NACC) {
        const float s = sred[0][threadIdx.x] + sred[1][threadIdx.x] +
                        sred[2][threadIdx.x] + sred[3][threadIdx.x];
        atomicAdd(&acc[b * 32 + threadIdx.x], s);
    }
}

__global__ void dba_solve(const float* __restrict__ acc,
                          const float* __restrict__ lmbda,
                          float* __restrict__ pose_out,
                          float* __restrict__ dp_ws, int B)
{
    const int b = blockIdx.x * blockDim.x + threadIdx.x;
    if (b >= B) return;
    float M[6][7];
    const float* a = acc + b * 32;
    int idx = 0;
#pragma unroll
    for (int i = 0; i < 6; ++i) {
#pragma unroll
        for (int j = i; j < 6; ++j) {
            const float t = a[idx++];
            M[i][j] = t;
            M[j][i] = t;
        }
    }
#pragma unroll
    for (int i = 0; i < 6; ++i) M[i][6] = a[21 + i];
    const float lam = lmbda[b];
#pragma unroll
    for (int i = 0; i < 6; ++i) M[i][i] += lam + 0.011f;  // lmbda*I + (0.01+0.001)*I

    // Gauss-Jordan, no pivoting (matrix strongly diagonally dominant SPD)
#pragma unroll
    for (int k = 0; k < 6; ++k) {
        const float piv = 1.0f / M[k][k];
#pragma unroll
        for (int j = 0; j < 7; ++j) M[k][j] *= piv;
#pragma unroll
        for (int i = 0; i < 6; ++i) {
            if (i == k) continue;
            const float f = M[i][k];
#pragma unroll
            for (int j = 0; j < 7; ++j) M[i][j] -= f * M[k][j];
        }
    }
#pragma unroll
    for (int i = 0; i < 6; ++i) {
        const float x = M[i][6];              // solution
        dp_ws[b * 6 + i] = x;                 // UNCLIPPED dp feeds pass 3
        pose_out[b * 6 + i] = fminf(fmaxf(x, -2.0f), 2.0f);
    }
}

__global__ __launch_bounds__(256) void dba_depth(
    const float* __restrict__ r, const float* __restrict__ w,
    const float* __restrict__ J_p, const float* __restrict__ J_d,
    const float* __restrict__ lmbda, const float* __restrict__ dp_ws,
    float* __restrict__ depth_out, int N)
{
    const int b = blockIdx.y;
    const float lam = lmbda[b];
    float dp[6];
#pragma unroll
    for (int i = 0; i < 6; ++i) dp[i] = dp_ws[b * 6 + i];

    const size_t base = (size_t)b * (size_t)N;
    const int P = N >> 1;
    const int stride = gridDim.x * blockDim.x;
    for (int pr = blockIdx.x * blockDim.x + threadIdx.x; pr < P; pr += stride) {
        const size_t p = base + (size_t)(pr << 1);
        const float4 rv = *(const float4*)(r + p * 2);
        const float4 wv = *(const float4*)(w + p * 2);
        const float4 jd = *(const float4*)(J_d + p * 2);
        const float4* jp = (const float4*)(J_p + p * 12);
        const float4 q0 = jp[0];
        const float4 q1 = jp[1];
        const float4 q2 = jp[2];
        const float4 q3 = jp[3];
        const float4 q4 = jp[4];
        const float4 q5 = jp[5];

        float2 outv;
        {
            const float ja[6] = {q0.x, q0.y, q0.z, q0.w, q1.x, q1.y};
            const float jb[6] = {q1.z, q1.w, q2.x, q2.y, q2.z, q2.w};
            float v = 0.f;
#pragma unroll
            for (int i = 0; i < 6; ++i)
                v += (ja[i] * jd.x + jb[i] * jd.y) * dp[i];
            v *= wv.x;
            const float hdd = wv.x * (jd.x * jd.x + jd.y * jd.y);
            const float inv = 1.0f / fmaxf(hdd + lam + wv.y, 1e-4f);
            const float gd  = wv.x * (jd.x * rv.x + jd.y * rv.y);
            outv.x = inv * (gd - v);
        }
        {
            const float ja[6] = {q3.x, q3.y, q3.z, q3.w, q4.x, q4.y};
            const float jb[6] = {q4.z, q4.w, q5.x, q5.y, q5.z, q5.w};
            float v = 0.f;
#pragma unroll
            for (int i = 0; i < 6; ++i)
                v += (ja[i] * jd.z + jb[i] * jd.w) * dp[i];
            v *= wv.z;
            const float hdd = wv.z * (jd.z * jd.z + jd.w * jd.w);
            const float inv = 1.0f / fmaxf(hdd + lam + wv.w, 1e-4f);
            const float gd  = wv.z * (jd.z * rv.z + jd.w * rv.w);
            outv.y = inv * (gd - v);
        }
        *(float2*)(depth_out + p) = outv;
    }
}

extern "C" void kernel_launch(void* const* d_in, const int* in_sizes, int n_in,
                              void* d_out, int out_size, void* d_ws, size_t ws_size,
                              hipStream_t stream)
{
    const float* r   = (const float*)d_in[0];
    const float* w   = (const float*)d_in[1];
    const float* J_p = (const float*)d_in[2];
    const float* J_d = (const float*)d_in[3];
    const float* lmb = (const float*)d_in[4];
    const int B = in_sizes[4];            // 16
    const int N = in_sizes[0] / (B * 2);  // 196608

    float* acc   = (float*)d_ws;           // B*32 floats of accumulators
    float* dp_ws = (float*)d_ws + B * 32;  // B*6 floats of unclipped dp
    float* out   = (float*)d_out;

    hipMemsetAsync(acc, 0, B * 32 * sizeof(float), stream);

    dim3 grid(192, B);  // 3072 blocks: ~24 waves/CU resident, 2 pairs/thread
    dba_reduce<<<grid, 256, 0, stream>>>(r, w, J_p, J_d, lmb, acc, N);
    dba_solve<<<1, 64, 0, stream>>>(acc, lmb, out, dp_ws, B);
    dba_depth<<<grid, 256, 0, stream>>>(r, w, J_p, J_d, lmb, dp_ws, out + B * 6, N);
}